// Round 1
// baseline (143.349 us; speedup 1.0000x reference)
//
#include <hip/hip_runtime.h>
#include <math.h>

#define BB 8
#define NN 512
#define FF 32
#define HH 64
#define TI 16
#define NEG_BIG (-1.0e30f)

// ---------------------------------------------------------------------------
// h = relu(x @ W_enc + b_enc); zi = h @ W_e1[:H] + b_e1; zj = h @ W_e1[H:]
// one block per (b,n) row, 64 threads (thread = output column)
// ---------------------------------------------------------------------------
__global__ __launch_bounds__(64) void encode_kernel(
    const float* __restrict__ x, const float* __restrict__ W_enc,
    const float* __restrict__ b_enc, const float* __restrict__ W_e1,
    const float* __restrict__ b_e1,
    float* __restrict__ h, float* __restrict__ zi, float* __restrict__ zj)
{
    const int row = blockIdx.x;     // 0..B*N-1
    const int t = threadIdx.x;      // 0..63
    __shared__ float xs[FF];
    __shared__ float hs[HH];
    if (t < FF) xs[t] = x[row * FF + t];
    __syncthreads();
    float acc = b_enc[t];
#pragma unroll
    for (int k = 0; k < FF; ++k) acc = fmaf(xs[k], W_enc[k * HH + t], acc);
    float hv = fmaxf(acc, 0.f);
    hs[t] = hv;
    h[row * HH + t] = hv;
    __syncthreads();
    float a1 = b_e1[t];   // fold b_e1 into zi so edge = relu(zi'[i,h]+zj[j,h])
    float a2 = 0.f;
#pragma unroll
    for (int k = 0; k < HH; ++k) {
        float hk = hs[k];
        a1 = fmaf(hk, W_e1[k * HH + t], a1);
        a2 = fmaf(hk, W_e1[(HH + k) * HH + t], a2);
    }
    zi[row * HH + t] = a1;
    zj[row * HH + t] = a2;
}

// ---------------------------------------------------------------------------
// logits[b,i,j] = sum_h relu(zi[b,i,h]+zj[b,j,h])*W_e2[h] + b_e2 ; diag=-inf
// adj = softmax_j(logits).  Block = (b, 16 i-rows), 256 threads.
// thread: ti = t>>4 (row), tj = t&15; 4 j's per thread per 64-wide j-tile.
// ---------------------------------------------------------------------------
__global__ __launch_bounds__(256) void adj_kernel(
    const float* __restrict__ zi, const float* __restrict__ zj,
    const float* __restrict__ W_e2, const float* __restrict__ b_e2,
    float* __restrict__ adj)
{
    const int nblk = NN / TI;                 // 32
    const int b = blockIdx.x / nblk;
    const int i0 = (blockIdx.x % nblk) * TI;
    const int t = threadIdx.x;
    const int ti = t >> 4;
    const int tj = t & 15;

    __shared__ float zis[TI][HH + 1];
    __shared__ float zjs[64][HH + 1];
    __shared__ float w2s[HH];
    __shared__ float lg[TI][NN];              // 32 KB

    if (t < HH) w2s[t] = W_e2[t];
    for (int idx = t; idx < TI * HH; idx += 256)
        zis[idx >> 6][idx & 63] = zi[(b * NN + i0 + (idx >> 6)) * HH + (idx & 63)];
    __syncthreads();

    const float be2 = b_e2[0];
    for (int j0 = 0; j0 < NN; j0 += 64) {
        for (int idx = t; idx < 64 * HH; idx += 256)
            zjs[idx >> 6][idx & 63] = zj[(b * NN + j0 + (idx >> 6)) * HH + (idx & 63)];
        __syncthreads();
        float acc[4] = {be2, be2, be2, be2};
#pragma unroll
        for (int k = 0; k < HH; ++k) {
            float ziv = zis[ti][k];
            float w = w2s[k];
#pragma unroll
            for (int s = 0; s < 4; ++s) {
                float v = ziv + zjs[tj + 16 * s][k];
                acc[s] = fmaf(fmaxf(v, 0.f), w, acc[s]);
            }
        }
#pragma unroll
        for (int s = 0; s < 4; ++s) {
            int j = j0 + tj + 16 * s;
            lg[ti][j] = (i0 + ti == j) ? NEG_BIG : acc[s];
        }
        __syncthreads();
    }

    // softmax over row ti, done by the 16 threads sharing ti (contig lanes)
    float m = NEG_BIG;
    for (int j = tj; j < NN; j += 16) m = fmaxf(m, lg[ti][j]);
#pragma unroll
    for (int off = 8; off >= 1; off >>= 1) m = fmaxf(m, __shfl_xor(m, off, 16));
    float sum = 0.f;
    for (int j = tj; j < NN; j += 16) sum += expf(lg[ti][j] - m);
#pragma unroll
    for (int off = 8; off >= 1; off >>= 1) sum += __shfl_xor(sum, off, 16);
    float inv = 1.0f / sum;
    for (int j = tj; j < NN; j += 16)
        adj[((size_t)(b * NN + i0 + ti)) * NN + j] = expf(lg[ti][j] - m) * inv;
}

// ---------------------------------------------------------------------------
// One GNN layer, fused: m = adj@h; mm = relu(m@W_msg+b); gi = mm@W_ih+b;
// gh = h@W_hh+b; GRU update -> h_out.  Block = (b, 16 i-rows), 256 threads.
// thread: hh = t&63 (column), q = t>>6; rows handled = q, q+4, q+8, q+12.
// ---------------------------------------------------------------------------
__global__ __launch_bounds__(256) void layer_kernel(
    const float* __restrict__ adj, const float* __restrict__ h_in,
    const float* __restrict__ W_msg, const float* __restrict__ b_msg,
    const float* __restrict__ W_ih, const float* __restrict__ b_ih,
    const float* __restrict__ W_hh, const float* __restrict__ b_hh,
    float* __restrict__ h_out)
{
    const int nblk = NN / TI;
    const int b = blockIdx.x / nblk;
    const int i0 = (blockIdx.x % nblk) * TI;
    const int t = threadIdx.x;
    const int hh = t & 63;
    const int q = t >> 6;

    __shared__ float adjs[TI][NN];            // 32 KB
    __shared__ float hold[TI][HH + 1];
    __shared__ float ms[TI][HH + 1];
    __shared__ float mms[TI][HH + 1];

    const float4* adj4 = (const float4*)(adj + ((size_t)(b * NN + i0)) * NN);
    float4* adjs4 = (float4*)(&adjs[0][0]);
    for (int idx = t; idx < TI * NN / 4; idx += 256) adjs4[idx] = adj4[idx];
    for (int idx = t; idx < TI * HH; idx += 256)
        hold[idx >> 6][idx & 63] = h_in[(b * NN + i0 + (idx >> 6)) * HH + (idx & 63)];
    __syncthreads();

    // m = adj @ h : adj reads are LDS broadcasts, h reads coalesced
    float macc[4] = {0.f, 0.f, 0.f, 0.f};
    for (int j = 0; j < NN; ++j) {
        float hv = h_in[((size_t)(b * NN + j)) * HH + hh];
#pragma unroll
        for (int p = 0; p < 4; ++p)
            macc[p] = fmaf(adjs[q + 4 * p][j], hv, macc[p]);
    }
#pragma unroll
    for (int p = 0; p < 4; ++p) ms[q + 4 * p][hh] = macc[p];
    __syncthreads();

    // mm = relu(m @ W_msg + b_msg)
    float mmacc[4];
#pragma unroll
    for (int p = 0; p < 4; ++p) mmacc[p] = b_msg[hh];
    for (int k = 0; k < HH; ++k) {
        float w = W_msg[k * HH + hh];
#pragma unroll
        for (int p = 0; p < 4; ++p)
            mmacc[p] = fmaf(ms[q + 4 * p][k], w, mmacc[p]);
    }
#pragma unroll
    for (int p = 0; p < 4; ++p) mms[q + 4 * p][hh] = fmaxf(mmacc[p], 0.f);
    __syncthreads();

    // gi/gh (3 gates each) + GRU, weights loaded once per k, shared over 4 rows
    float g0[4], g1[4], g2[4], g3[4], g4[4], g5[4];
#pragma unroll
    for (int p = 0; p < 4; ++p) {
        g0[p] = b_ih[hh]; g1[p] = b_ih[64 + hh]; g2[p] = b_ih[128 + hh];
        g3[p] = b_hh[hh]; g4[p] = b_hh[64 + hh]; g5[p] = b_hh[128 + hh];
    }
    for (int k = 0; k < HH; ++k) {
        float wi0 = W_ih[k * 192 + hh];
        float wi1 = W_ih[k * 192 + 64 + hh];
        float wi2 = W_ih[k * 192 + 128 + hh];
        float wh0 = W_hh[k * 192 + hh];
        float wh1 = W_hh[k * 192 + 64 + hh];
        float wh2 = W_hh[k * 192 + 128 + hh];
#pragma unroll
        for (int p = 0; p < 4; ++p) {
            int r = q + 4 * p;
            float mv = mms[r][k];
            float hv = hold[r][k];
            g0[p] = fmaf(mv, wi0, g0[p]);
            g1[p] = fmaf(mv, wi1, g1[p]);
            g2[p] = fmaf(mv, wi2, g2[p]);
            g3[p] = fmaf(hv, wh0, g3[p]);
            g4[p] = fmaf(hv, wh1, g4[p]);
            g5[p] = fmaf(hv, wh2, g5[p]);
        }
    }
#pragma unroll
    for (int p = 0; p < 4; ++p) {
        int r = q + 4 * p;
        float rr = 1.f / (1.f + expf(-(g0[p] + g3[p])));
        float zz = 1.f / (1.f + expf(-(g1[p] + g4[p])));
        float nn = tanhf(g2[p] + rr * g5[p]);
        float hnew = (1.f - zz) * nn + zz * hold[r][hh];
        h_out[((size_t)(b * NN + i0 + r)) * HH + hh] = hnew;
    }
}

// ---------------------------------------------------------------------------
// out[b] = mean_i(h[b,i,:]) @ W_out + b_out ; one wave per batch
// ---------------------------------------------------------------------------
__global__ __launch_bounds__(64) void readout_kernel(
    const float* __restrict__ h, const float* __restrict__ W_out,
    const float* __restrict__ b_out, float* __restrict__ out)
{
    const int b = blockIdx.x;
    const int t = threadIdx.x;
    float acc = 0.f;
    for (int i = 0; i < NN; ++i) acc += h[((size_t)(b * NN + i)) * HH + t];
    float v = (acc * (1.0f / NN)) * W_out[t];
#pragma unroll
    for (int off = 32; off >= 1; off >>= 1) v += __shfl_down(v, off);
    if (t == 0) out[b] = v + b_out[0];
}

extern "C" void kernel_launch(void* const* d_in, const int* in_sizes, int n_in,
                              void* d_out, int out_size, void* d_ws, size_t ws_size,
                              hipStream_t stream)
{
    const float* x     = (const float*)d_in[0];
    const float* W_enc = (const float*)d_in[1];
    const float* b_enc = (const float*)d_in[2];
    const float* W_e1  = (const float*)d_in[3];
    const float* b_e1  = (const float*)d_in[4];
    const float* W_e2  = (const float*)d_in[5];
    const float* b_e2  = (const float*)d_in[6];
    const float* W_msg = (const float*)d_in[7];
    const float* b_msg = (const float*)d_in[8];
    const float* W_ih  = (const float*)d_in[9];
    const float* b_ih  = (const float*)d_in[10];
    const float* W_hh  = (const float*)d_in[11];
    const float* b_hh  = (const float*)d_in[12];
    const float* W_out = (const float*)d_in[13];
    const float* b_out = (const float*)d_in[14];
    float* out = (float*)d_out;

    float* ws = (float*)d_ws;
    float* h0  = ws;                       // B*N*H = 262144 floats
    float* h1  = h0 + BB * NN * HH;
    float* zi  = h1 + BB * NN * HH;
    float* zj  = zi + BB * NN * HH;
    float* adj = zj + BB * NN * HH;        // B*N*N = 2097152 floats

    encode_kernel<<<BB * NN, 64, 0, stream>>>(x, W_enc, b_enc, W_e1, b_e1, h0, zi, zj);
    adj_kernel<<<BB * (NN / TI), 256, 0, stream>>>(zi, zj, W_e2, b_e2, adj);
    layer_kernel<<<BB * (NN / TI), 256, 0, stream>>>(
        adj, h0, W_msg, b_msg, W_ih, b_ih, W_hh, b_hh, h1);
    layer_kernel<<<BB * (NN / TI), 256, 0, stream>>>(
        adj, h1, W_msg + HH * HH, b_msg + HH,
        W_ih + HH * 3 * HH, b_ih + 3 * HH,
        W_hh + HH * 3 * HH, b_hh + 3 * HH, h0);
    readout_kernel<<<BB, 64, 0, stream>>>(h0, W_out, b_out, out);
}

// Round 2
// 143.264 us; speedup vs baseline: 1.0006x; 1.0006x over previous
//
#include <hip/hip_runtime.h>
#include <math.h>

#define BB 8
#define NN 512
#define FF 32
#define HH 64
#define NEG_BIG (-1.0e30f)

__device__ __forceinline__ float lane_bcast(float v, int l) {
    return __int_as_float(__builtin_amdgcn_readlane(__float_as_int(v), l));
}

// ---------------------------------------------------------------------------
// encode: h = relu(x@W_enc+b); zi = h@W_e1[:H]+b_e1; zj = h@W_e1[H:]
// block = 16 rows, 256 threads; thread: hh=t&63 (col), q=t>>6, rows q+4p
// ---------------------------------------------------------------------------
__global__ __launch_bounds__(256) void encode_kernel(
    const float* __restrict__ x, const float* __restrict__ W_enc,
    const float* __restrict__ b_enc, const float* __restrict__ W_e1,
    const float* __restrict__ b_e1,
    float* __restrict__ h, float* __restrict__ zi, float* __restrict__ zj)
{
    const int row0 = blockIdx.x * 16;          // global row in [0, B*N)
    const int t = threadIdx.x;
    const int hh = t & 63;
    const int q = t >> 6;

    __shared__ float xs[16][33];
    __shared__ float hs[16][65];

    for (int idx = t; idx < 16 * FF; idx += 256)
        xs[idx >> 5][idx & 31] = x[row0 * FF + idx];
    __syncthreads();

    float acc[4];
#pragma unroll
    for (int p = 0; p < 4; ++p) acc[p] = b_enc[hh];
#pragma unroll
    for (int k = 0; k < FF; ++k) {
        float w = W_enc[k * HH + hh];
#pragma unroll
        for (int p = 0; p < 4; ++p) acc[p] = fmaf(xs[q + 4 * p][k], w, acc[p]);
    }
#pragma unroll
    for (int p = 0; p < 4; ++p) {
        float hv = fmaxf(acc[p], 0.f);
        hs[q + 4 * p][hh] = hv;
        h[(row0 + q + 4 * p) * HH + hh] = hv;
    }
    __syncthreads();

    float z1[4], z2[4];
#pragma unroll
    for (int p = 0; p < 4; ++p) { z1[p] = b_e1[hh]; z2[p] = 0.f; }
#pragma unroll
    for (int k = 0; k < HH; ++k) {
        float wa = W_e1[k * HH + hh];
        float wb = W_e1[(HH + k) * HH + hh];
#pragma unroll
        for (int p = 0; p < 4; ++p) {
            float hk = hs[q + 4 * p][k];
            z1[p] = fmaf(hk, wa, z1[p]);
            z2[p] = fmaf(hk, wb, z2[p]);
        }
    }
#pragma unroll
    for (int p = 0; p < 4; ++p) {
        zi[(row0 + q + 4 * p) * HH + hh] = z1[p];
        zj[(row0 + q + 4 * p) * HH + hh] = z2[p];
    }
}

// ---------------------------------------------------------------------------
// adj: logits[i,j] = sum_k relu(zi[i,k]+zj[j,k])*W_e2[k] + b_e2, diag=-inf,
// softmax over j.  Block = (b, 4 i-rows), 256 threads; wave ti owns row
// i0+ti, lane tj owns j = tj+64s (s=0..7).  Softmax fully in registers.
// zj staged in k-quarters: zjs[512][17] (2-way bank alias = free).
// ---------------------------------------------------------------------------
__global__ __launch_bounds__(256) void adj_kernel(
    const float* __restrict__ zi, const float* __restrict__ zj,
    const float* __restrict__ W_e2, const float* __restrict__ b_e2,
    float* __restrict__ adj)
{
    const int b = blockIdx.x >> 7;
    const int i0 = (blockIdx.x & 127) * 4;
    const int t = threadIdx.x;
    const int ti = t >> 6;
    const int tj = t & 63;

    __shared__ float zis[4][65];
    __shared__ float zjs[NN][17];

    if (t < 4 * HH)
        zis[t >> 6][t & 63] = zi[(b * NN + i0 + (t >> 6)) * HH + (t & 63)];

    const float be2 = b_e2[0];
    float acc[8];
#pragma unroll
    for (int s = 0; s < 8; ++s) acc[s] = be2;

    for (int kp = 0; kp < 4; ++kp) {
        __syncthreads();
        for (int idx = t; idx < NN * 16; idx += 256) {
            int row = idx >> 4, c = idx & 15;
            zjs[row][c] = zj[(b * NN + row) * HH + kp * 16 + c];
        }
        __syncthreads();
#pragma unroll
        for (int c = 0; c < 16; ++c) {
            int k = kp * 16 + c;
            float zv = zis[ti][k];
            float w = W_e2[k];
#pragma unroll
            for (int s = 0; s < 8; ++s) {
                float v = zv + zjs[tj + 64 * s][c];
                acc[s] = fmaf(fmaxf(v, 0.f), w, acc[s]);
            }
        }
    }

    const int irow = i0 + ti;
#pragma unroll
    for (int s = 0; s < 8; ++s)
        if (tj + 64 * s == irow) acc[s] = NEG_BIG;

    float m = acc[0];
#pragma unroll
    for (int s = 1; s < 8; ++s) m = fmaxf(m, acc[s]);
#pragma unroll
    for (int off = 32; off >= 1; off >>= 1) m = fmaxf(m, __shfl_xor(m, off));

    float e[8], sum = 0.f;
#pragma unroll
    for (int s = 0; s < 8; ++s) { e[s] = expf(acc[s] - m); sum += e[s]; }
#pragma unroll
    for (int off = 32; off >= 1; off >>= 1) sum += __shfl_xor(sum, off);
    float inv = 1.0f / sum;

    float* arow = adj + ((size_t)(b * NN + irow)) * NN;
#pragma unroll
    for (int s = 0; s < 8; ++s) arow[tj + 64 * s] = e[s] * inv;
}

// ---------------------------------------------------------------------------
// msg: m = adj@h ; mm = relu(m@W_msg + b_msg).  Block = (b, 4 i-rows),
// 256 threads; wave ti owns row i0+ti, lane tj owns column tj.
// adj row lives in 8 regs/lane, broadcast via v_readlane; h tiles in LDS.
// m row stays wave-distributed (lane k holds m[row][k]) -> msg GEMM via
// readlane, no LDS round-trip.
// ---------------------------------------------------------------------------
__global__ __launch_bounds__(256) void msg_kernel(
    const float* __restrict__ adj, const float* __restrict__ h_in,
    const float* __restrict__ W_msg, const float* __restrict__ b_msg,
    float* __restrict__ mm_out)
{
    const int b = blockIdx.x >> 7;
    const int i0 = (blockIdx.x & 127) * 4;
    const int t = threadIdx.x;
    const int ti = t >> 6;
    const int tj = t & 63;
    const int irow = b * NN + i0 + ti;

    __shared__ float hs[64][68];

    float a[8];
    const float* arow = adj + (size_t)irow * NN;
#pragma unroll
    for (int s = 0; s < 8; ++s) a[s] = arow[tj + 64 * s];

    float acc = 0.f;
    for (int s = 0; s < 8; ++s) {
        __syncthreads();
        const float4* hp = (const float4*)(h_in + (b * NN + 64 * s) * HH);
        for (int idx = t; idx < 64 * 16; idx += 256) {
            int row = idx >> 4, c4 = idx & 15;
            *(float4*)&hs[row][c4 * 4] = hp[idx];
        }
        __syncthreads();
#pragma unroll
        for (int l = 0; l < 64; ++l) {
            float av = lane_bcast(a[s], l);
            acc = fmaf(av, hs[l][tj], acc);
        }
    }

    // mm[row][tj] = relu(sum_k m[row][k] * W_msg[k][tj] + b_msg[tj])
    float mm = b_msg[tj];
#pragma unroll
    for (int k = 0; k < HH; ++k) {
        float mv = lane_bcast(acc, k);
        mm = fmaf(mv, W_msg[k * HH + tj], mm);
    }
    mm_out[(size_t)irow * HH + tj] = fmaxf(mm, 0.f);
}

// ---------------------------------------------------------------------------
// gru: gi = mm@W_ih+b_ih; gh = h@W_hh+b_hh; GRU update -> h_out.
// Block = (b, 8 i-rows), 256 threads; hh=t&63, q=t>>6, rows q+4p (p=0..1).
// Weights staged to LDS in k-halves (every wave otherwise streams 96 KB).
// ---------------------------------------------------------------------------
__global__ __launch_bounds__(256) void gru_kernel(
    const float* __restrict__ mm, const float* __restrict__ h_in,
    const float* __restrict__ W_ih, const float* __restrict__ b_ih,
    const float* __restrict__ W_hh, const float* __restrict__ b_hh,
    float* __restrict__ h_out)
{
    const int b = blockIdx.x >> 6;
    const int i0 = (blockIdx.x & 63) * 8;
    const int t = threadIdx.x;
    const int hh = t & 63;
    const int q = t >> 6;

    __shared__ float wih[32][196];
    __shared__ float whh[32][196];
    __shared__ float mms[8][65];
    __shared__ float hold[8][65];

    for (int idx = t; idx < 8 * HH; idx += 256) {
        int row = idx >> 6, c = idx & 63;
        mms[row][c]  = mm[(b * NN + i0 + row) * HH + c];
        hold[row][c] = h_in[(b * NN + i0 + row) * HH + c];
    }

    float g0[2], g1[2], g2[2], g3[2], g4[2], g5[2];
#pragma unroll
    for (int p = 0; p < 2; ++p) {
        g0[p] = b_ih[hh]; g1[p] = b_ih[64 + hh]; g2[p] = b_ih[128 + hh];
        g3[p] = b_hh[hh]; g4[p] = b_hh[64 + hh]; g5[p] = b_hh[128 + hh];
    }

    for (int half = 0; half < 2; ++half) {
        const int k0 = half * 32;
        __syncthreads();
        {
            const float4* wi4 = (const float4*)(W_ih + k0 * 192);
            const float4* wh4 = (const float4*)(W_hh + k0 * 192);
            for (int i4 = t; i4 < 32 * 48; i4 += 256) {
                int kk = i4 / 48;
                int c4 = i4 - kk * 48;
                *(float4*)&wih[kk][c4 * 4] = wi4[i4];
                *(float4*)&whh[kk][c4 * 4] = wh4[i4];
            }
        }
        __syncthreads();
#pragma unroll
        for (int kk = 0; kk < 32; ++kk) {
            int k = k0 + kk;
            float wi0 = wih[kk][hh], wi1 = wih[kk][64 + hh], wi2 = wih[kk][128 + hh];
            float wh0 = whh[kk][hh], wh1 = whh[kk][64 + hh], wh2 = whh[kk][128 + hh];
#pragma unroll
            for (int p = 0; p < 2; ++p) {
                float mv = mms[q + 4 * p][k];
                float hv = hold[q + 4 * p][k];
                g0[p] = fmaf(mv, wi0, g0[p]);
                g1[p] = fmaf(mv, wi1, g1[p]);
                g2[p] = fmaf(mv, wi2, g2[p]);
                g3[p] = fmaf(hv, wh0, g3[p]);
                g4[p] = fmaf(hv, wh1, g4[p]);
                g5[p] = fmaf(hv, wh2, g5[p]);
            }
        }
    }

#pragma unroll
    for (int p = 0; p < 2; ++p) {
        int r = q + 4 * p;
        float rr = 1.f / (1.f + expf(-(g0[p] + g3[p])));
        float zz = 1.f / (1.f + expf(-(g1[p] + g4[p])));
        float nn = tanhf(g2[p] + rr * g5[p]);
        float hprev = hold[r][hh];
        h_out[((size_t)(b * NN + i0 + r)) * HH + hh] = (1.f - zz) * nn + zz * hprev;
    }
}

// ---------------------------------------------------------------------------
// readout: out[b] = mean_i(h[b,i,:]) @ W_out + b_out
// ---------------------------------------------------------------------------
__global__ __launch_bounds__(256) void readout_kernel(
    const float* __restrict__ h, const float* __restrict__ W_out,
    const float* __restrict__ b_out, float* __restrict__ out)
{
    const int b = blockIdx.x;
    const int t = threadIdx.x;
    const int hh = t & 63;
    const int q = t >> 6;
    __shared__ float red[4][65];

    float s = 0.f;
    for (int i = q; i < NN; i += 4) s += h[((size_t)(b * NN + i)) * HH + hh];
    red[q][hh] = s;
    __syncthreads();
    if (q == 0) {
        float tot = red[0][hh] + red[1][hh] + red[2][hh] + red[3][hh];
        float v = tot * (1.0f / NN) * W_out[hh];
#pragma unroll
        for (int off = 32; off >= 1; off >>= 1) v += __shfl_xor(v, off);
        if (hh == 0) out[b] = v + b_out[0];
    }
}

extern "C" void kernel_launch(void* const* d_in, const int* in_sizes, int n_in,
                              void* d_out, int out_size, void* d_ws, size_t ws_size,
                              hipStream_t stream)
{
    const float* x     = (const float*)d_in[0];
    const float* W_enc = (const float*)d_in[1];
    const float* b_enc = (const float*)d_in[2];
    const float* W_e1  = (const float*)d_in[3];
    const float* b_e1  = (const float*)d_in[4];
    const float* W_e2  = (const float*)d_in[5];
    const float* b_e2  = (const float*)d_in[6];
    const float* W_msg = (const float*)d_in[7];
    const float* b_msg = (const float*)d_in[8];
    const float* W_ih  = (const float*)d_in[9];
    const float* b_ih  = (const float*)d_in[10];
    const float* W_hh  = (const float*)d_in[11];
    const float* b_hh  = (const float*)d_in[12];
    const float* W_out = (const float*)d_in[13];
    const float* b_out = (const float*)d_in[14];
    float* out = (float*)d_out;

    float* ws = (float*)d_ws;
    float* h0  = ws;                        // B*N*H
    float* h1  = h0 + BB * NN * HH;
    float* zi  = h1 + BB * NN * HH;
    float* zj  = zi + BB * NN * HH;
    float* mmb = zj + BB * NN * HH;
    float* adj = mmb + BB * NN * HH;        // B*N*N

    encode_kernel<<<BB * NN / 16, 256, 0, stream>>>(x, W_enc, b_enc, W_e1, b_e1, h0, zi, zj);
    adj_kernel<<<BB * (NN / 4), 256, 0, stream>>>(zi, zj, W_e2, b_e2, adj);

    // layer 0
    msg_kernel<<<BB * (NN / 4), 256, 0, stream>>>(adj, h0, W_msg, b_msg, mmb);
    gru_kernel<<<BB * (NN / 8), 256, 0, stream>>>(mmb, h0, W_ih, b_ih, W_hh, b_hh, h1);
    // layer 1
    msg_kernel<<<BB * (NN / 4), 256, 0, stream>>>(adj, h1, W_msg + HH * HH, b_msg + HH, mmb);
    gru_kernel<<<BB * (NN / 8), 256, 0, stream>>>(mmb, h1,
        W_ih + HH * 3 * HH, b_ih + 3 * HH, W_hh + HH * 3 * HH, b_hh + 3 * HH, h0);

    readout_kernel<<<BB, 256, 0, stream>>>(h0, W_out, b_out, out);
}

// Round 3
// 138.815 us; speedup vs baseline: 1.0327x; 1.0320x over previous
//
#include <hip/hip_runtime.h>
#include <math.h>

#define BB 8
#define NN 512
#define FF 32
#define HH 64
#define NEG_BIG (-1.0e30f)

__device__ __forceinline__ float lane_bcast(float v, int l) {
    return __int_as_float(__builtin_amdgcn_readlane(__float_as_int(v), l));
}

// ---------------------------------------------------------------------------
// encode: h = relu(x@W_enc+b); zi = h@W_e1[:H]+b_e1; zj = h@W_e1[H:]
// block = 16 rows, 256 threads; thread: hh=t&63 (col), q=t>>6, rows q+4p
// ---------------------------------------------------------------------------
__global__ __launch_bounds__(256) void encode_kernel(
    const float* __restrict__ x, const float* __restrict__ W_enc,
    const float* __restrict__ b_enc, const float* __restrict__ W_e1,
    const float* __restrict__ b_e1,
    float* __restrict__ h, float* __restrict__ zi, float* __restrict__ zj)
{
    const int row0 = blockIdx.x * 16;
    const int t = threadIdx.x;
    const int hh = t & 63;
    const int q = t >> 6;

    __shared__ float xs[16][33];
    __shared__ float hs[16][65];

    for (int idx = t; idx < 16 * FF; idx += 256)
        xs[idx >> 5][idx & 31] = x[row0 * FF + idx];
    __syncthreads();

    float acc[4];
#pragma unroll
    for (int p = 0; p < 4; ++p) acc[p] = b_enc[hh];
#pragma unroll
    for (int k = 0; k < FF; ++k) {
        float w = W_enc[k * HH + hh];
#pragma unroll
        for (int p = 0; p < 4; ++p) acc[p] = fmaf(xs[q + 4 * p][k], w, acc[p]);
    }
#pragma unroll
    for (int p = 0; p < 4; ++p) {
        float hv = fmaxf(acc[p], 0.f);
        hs[q + 4 * p][hh] = hv;
        h[(row0 + q + 4 * p) * HH + hh] = hv;
    }
    __syncthreads();

    float z1[4], z2[4];
#pragma unroll
    for (int p = 0; p < 4; ++p) { z1[p] = b_e1[hh]; z2[p] = 0.f; }
#pragma unroll
    for (int k = 0; k < HH; ++k) {
        float wa = W_e1[k * HH + hh];
        float wb = W_e1[(HH + k) * HH + hh];
#pragma unroll
        for (int p = 0; p < 4; ++p) {
            float hk = hs[q + 4 * p][k];
            z1[p] = fmaf(hk, wa, z1[p]);
            z2[p] = fmaf(hk, wb, z2[p]);
        }
    }
#pragma unroll
    for (int p = 0; p < 4; ++p) {
        zi[(row0 + q + 4 * p) * HH + hh] = z1[p];
        zj[(row0 + q + 4 * p) * HH + hh] = z2[p];
    }
}

// ---------------------------------------------------------------------------
// adj: logits[i,j] = sum_k relu(zi[i,k]+zj[j,k])*W_e2[k] + b_e2, diag masked,
// softmax over j.  Block = (b, 8 rows), 256 threads.  Wave q owns j-quarter
// [128q,128q+128): lane tj handles j0=128q+tj and j1=j0+64.
// zi read via scalar loads (wave-uniform row/k); zj staged in k-slices.
// Softmax: shfl reduce in-wave + tiny LDS cross-wave reduce.
// ---------------------------------------------------------------------------
__global__ __launch_bounds__(256) void adj_kernel(
    const float* __restrict__ zi, const float* __restrict__ zj,
    const float* __restrict__ W_e2, const float* __restrict__ b_e2,
    float* __restrict__ adj)
{
    const int b = blockIdx.x >> 6;
    const int i0 = (blockIdx.x & 63) * 8;
    const int t = threadIdx.x;
    const int q = __builtin_amdgcn_readfirstlane(t >> 6);
    const int tj = t & 63;
    const int j0 = q * 128 + tj;
    const int j1 = j0 + 64;

    __shared__ float zjs[NN][17];
    __shared__ float red[4][8];

    const float be2 = b_e2[0];
    float acc0[8], acc1[8];
#pragma unroll
    for (int r = 0; r < 8; ++r) { acc0[r] = be2; acc1[r] = be2; }

    const float* zib = zi + (b * NN + i0) * HH;   // uniform base -> s_load

    for (int kp = 0; kp < 4; ++kp) {
        __syncthreads();
        for (int idx = t; idx < NN * 16; idx += 256) {
            int row = idx >> 4, c = idx & 15;
            zjs[row][c] = zj[(b * NN + row) * HH + kp * 16 + c];
        }
        __syncthreads();
#pragma unroll
        for (int c = 0; c < 16; ++c) {
            const int k = kp * 16 + c;
            const float w = W_e2[k];
            const float zj0 = zjs[j0][c];
            const float zj1 = zjs[j1][c];
#pragma unroll
            for (int r = 0; r < 8; ++r) {
                const float zv = zib[r * HH + k];   // scalar load
                acc0[r] = fmaf(fmaxf(zv + zj0, 0.f), w, acc0[r]);
                acc1[r] = fmaf(fmaxf(zv + zj1, 0.f), w, acc1[r]);
            }
        }
    }

    // diagonal mask
#pragma unroll
    for (int r = 0; r < 8; ++r) {
        const int row = i0 + r;
        if (j0 == row) acc0[r] = NEG_BIG;
        if (j1 == row) acc1[r] = NEG_BIG;
    }

    // row max: in-wave shfl, then cross-wave via LDS
    float wmax[8];
#pragma unroll
    for (int r = 0; r < 8; ++r) {
        float m = fmaxf(acc0[r], acc1[r]);
#pragma unroll
        for (int off = 32; off >= 1; off >>= 1) m = fmaxf(m, __shfl_xor(m, off));
        wmax[r] = m;
    }
    if (tj == 0) {
#pragma unroll
        for (int r = 0; r < 8; ++r) red[q][r] = wmax[r];
    }
    __syncthreads();
    float M[8];
#pragma unroll
    for (int r = 0; r < 8; ++r)
        M[r] = fmaxf(fmaxf(red[0][r], red[1][r]), fmaxf(red[2][r], red[3][r]));
    __syncthreads();   // red reuse (WAR)

    float e0[8], e1[8];
#pragma unroll
    for (int r = 0; r < 8; ++r) {
        e0[r] = __expf(acc0[r] - M[r]);
        e1[r] = __expf(acc1[r] - M[r]);
        float s = e0[r] + e1[r];
#pragma unroll
        for (int off = 32; off >= 1; off >>= 1) s += __shfl_xor(s, off);
        if (tj == 0) red[q][r] = s;
    }
    __syncthreads();
#pragma unroll
    for (int r = 0; r < 8; ++r) {
        float inv = 1.0f / (red[0][r] + red[1][r] + red[2][r] + red[3][r]);
        float* arow = adj + ((size_t)(b * NN + i0 + r)) * NN;
        arow[j0] = e0[r] * inv;
        arow[j1] = e1[r] * inv;
    }
}

// ---------------------------------------------------------------------------
// layer (msg + GRU fused): m = adj@h; mm = relu(m@W_msg+b); gates; GRU.
// Block = (b, 16 rows), 256 threads; thread (q,hh) owns rows q+4p, col hh.
// adj rows read via scalar loads (wave-uniform); h streamed coalesced from
// L2; m/mm/h stay in registers, broadcast via v_readlane.
// ---------------------------------------------------------------------------
__global__ __launch_bounds__(256) void layer_kernel(
    const float* __restrict__ adj, const float* __restrict__ h_in,
    const float* __restrict__ W_msg, const float* __restrict__ b_msg,
    const float* __restrict__ W_ih, const float* __restrict__ b_ih,
    const float* __restrict__ W_hh, const float* __restrict__ b_hh,
    float* __restrict__ h_out)
{
    const int b = blockIdx.x >> 5;
    const int i0 = (blockIdx.x & 31) * 16;
    const int t = threadIdx.x;
    const int hh = t & 63;
    const int qu = __builtin_amdgcn_readfirstlane(t >> 6);

    __shared__ union {
        float wmsg[HH][HH];
        struct { float wih[32][196]; float whh[32][196]; } g;
    } U;

    // stage W_msg up front (phase A doesn't touch LDS)
    {
        const float4* w4 = (const float4*)W_msg;
        for (int i4 = t; i4 < HH * HH / 4; i4 += 256)
            ((float4*)&U.wmsg[0][0])[i4] = w4[i4];
    }
    __syncthreads();

    float hv[4], m[4];
#pragma unroll
    for (int p = 0; p < 4; ++p) {
        hv[p] = h_in[(b * NN + i0 + qu + 4 * p) * HH + hh];
        m[p] = 0.f;
    }

    // phase A: m = adj @ h
    const float* hb = h_in + (size_t)b * NN * HH;
    const float* a0 = adj + ((size_t)(b * NN + i0 + qu)) * NN;
    const float* a1 = a0 + 4 * NN;
    const float* a2 = a0 + 8 * NN;
    const float* a3 = a0 + 12 * NN;
#pragma unroll 8
    for (int j = 0; j < NN; ++j) {
        float hvv = hb[j * HH + hh];
        m[0] = fmaf(a0[j], hvv, m[0]);
        m[1] = fmaf(a1[j], hvv, m[1]);
        m[2] = fmaf(a2[j], hvv, m[2]);
        m[3] = fmaf(a3[j], hvv, m[3]);
    }

    // phase B: mm = relu(m @ W_msg + b_msg)
    float mm[4];
#pragma unroll
    for (int p = 0; p < 4; ++p) mm[p] = b_msg[hh];
#pragma unroll 8
    for (int k = 0; k < HH; ++k) {
        float w = U.wmsg[k][hh];
#pragma unroll
        for (int p = 0; p < 4; ++p)
            mm[p] = fmaf(lane_bcast(m[p], k), w, mm[p]);
    }
#pragma unroll
    for (int p = 0; p < 4; ++p) mm[p] = fmaxf(mm[p], 0.f);

    // phase C: GRU gates, weights staged in k-halves
    float g0[4], g1[4], g2[4], g3[4], g4[4], g5[4];
#pragma unroll
    for (int p = 0; p < 4; ++p) {
        g0[p] = b_ih[hh]; g1[p] = b_ih[64 + hh]; g2[p] = b_ih[128 + hh];
        g3[p] = b_hh[hh]; g4[p] = b_hh[64 + hh]; g5[p] = b_hh[128 + hh];
    }
    for (int half = 0; half < 2; ++half) {
        const int k0 = half * 32;
        __syncthreads();   // protect U (phase B read / previous half read)
        {
            const float4* wi4 = (const float4*)(W_ih + k0 * 192);
            const float4* wh4 = (const float4*)(W_hh + k0 * 192);
            for (int i4 = t; i4 < 32 * 48; i4 += 256) {
                int kk = i4 / 48, c4 = i4 - kk * 48;
                *(float4*)&U.g.wih[kk][c4 * 4] = wi4[i4];
                *(float4*)&U.g.whh[kk][c4 * 4] = wh4[i4];
            }
        }
        __syncthreads();
#pragma unroll 4
        for (int kk = 0; kk < 32; ++kk) {
            const int k = k0 + kk;
            float wi0 = U.g.wih[kk][hh], wi1 = U.g.wih[kk][64 + hh], wi2 = U.g.wih[kk][128 + hh];
            float wh0 = U.g.whh[kk][hh], wh1 = U.g.whh[kk][64 + hh], wh2 = U.g.whh[kk][128 + hh];
#pragma unroll
            for (int p = 0; p < 4; ++p) {
                float mv = lane_bcast(mm[p], k);
                float hvk = lane_bcast(hv[p], k);
                g0[p] = fmaf(mv, wi0, g0[p]);
                g1[p] = fmaf(mv, wi1, g1[p]);
                g2[p] = fmaf(mv, wi2, g2[p]);
                g3[p] = fmaf(hvk, wh0, g3[p]);
                g4[p] = fmaf(hvk, wh1, g4[p]);
                g5[p] = fmaf(hvk, wh2, g5[p]);
            }
        }
    }

#pragma unroll
    for (int p = 0; p < 4; ++p) {
        float rr = 1.f / (1.f + __expf(-(g0[p] + g3[p])));
        float zz = 1.f / (1.f + __expf(-(g1[p] + g4[p])));
        float nnv = tanhf(g2[p] + rr * g5[p]);
        h_out[((size_t)(b * NN + i0 + qu + 4 * p)) * HH + hh] =
            (1.f - zz) * nnv + zz * hv[p];
    }
}

// ---------------------------------------------------------------------------
// readout: out[b] = mean_i(h[b,i,:]) @ W_out + b_out
// ---------------------------------------------------------------------------
__global__ __launch_bounds__(256) void readout_kernel(
    const float* __restrict__ h, const float* __restrict__ W_out,
    const float* __restrict__ b_out, float* __restrict__ out)
{
    const int b = blockIdx.x;
    const int t = threadIdx.x;
    const int hh = t & 63;
    const int q = t >> 6;
    __shared__ float red[4][65];

    float s = 0.f;
    for (int i = q; i < NN; i += 4) s += h[((size_t)(b * NN + i)) * HH + hh];
    red[q][hh] = s;
    __syncthreads();
    if (q == 0) {
        float tot = red[0][hh] + red[1][hh] + red[2][hh] + red[3][hh];
        float v = tot * (1.0f / NN) * W_out[hh];
#pragma unroll
        for (int off = 32; off >= 1; off >>= 1) v += __shfl_xor(v, off);
        if (hh == 0) out[b] = v + b_out[0];
    }
}

extern "C" void kernel_launch(void* const* d_in, const int* in_sizes, int n_in,
                              void* d_out, int out_size, void* d_ws, size_t ws_size,
                              hipStream_t stream)
{
    const float* x     = (const float*)d_in[0];
    const float* W_enc = (const float*)d_in[1];
    const float* b_enc = (const float*)d_in[2];
    const float* W_e1  = (const float*)d_in[3];
    const float* b_e1  = (const float*)d_in[4];
    const float* W_e2  = (const float*)d_in[5];
    const float* b_e2  = (const float*)d_in[6];
    const float* W_msg = (const float*)d_in[7];
    const float* b_msg = (const float*)d_in[8];
    const float* W_ih  = (const float*)d_in[9];
    const float* b_ih  = (const float*)d_in[10];
    const float* W_hh  = (const float*)d_in[11];
    const float* b_hh  = (const float*)d_in[12];
    const float* W_out = (const float*)d_in[13];
    const float* b_out = (const float*)d_in[14];
    float* out = (float*)d_out;

    float* ws = (float*)d_ws;
    float* h0  = ws;                        // B*N*H
    float* h1  = h0 + BB * NN * HH;
    float* zi  = h1 + BB * NN * HH;
    float* zj  = zi + BB * NN * HH;
    float* adjw = zj + BB * NN * HH;        // B*N*N

    encode_kernel<<<BB * NN / 16, 256, 0, stream>>>(x, W_enc, b_enc, W_e1, b_e1, h0, zi, zj);
    adj_kernel<<<BB * (NN / 8), 256, 0, stream>>>(zi, zj, W_e2, b_e2, adjw);

    layer_kernel<<<BB * (NN / 16), 256, 0, stream>>>(
        adjw, h0, W_msg, b_msg, W_ih, b_ih, W_hh, b_hh, h1);
    layer_kernel<<<BB * (NN / 16), 256, 0, stream>>>(
        adjw, h1, W_msg + HH * HH, b_msg + HH,
        W_ih + HH * 3 * HH, b_ih + 3 * HH, W_hh + HH * 3 * HH, b_hh + 3 * HH, h0);

    readout_kernel<<<BB, 256, 0, stream>>>(h0, W_out, b_out, out);
}

// Round 5
// 109.457 us; speedup vs baseline: 1.3096x; 1.2682x over previous
//
#include <hip/hip_runtime.h>
#include <math.h>

#define BB 8
#define NN 512
#define FF 32
#define HH 64
#define NEG_BIG (-1.0e30f)

__device__ __forceinline__ float lane_bcast(float v, int l) {
    return __int_as_float(__builtin_amdgcn_readlane(__float_as_int(v), l));
}

// ---------------------------------------------------------------------------
// encode: h = relu(x@W_enc+b); zi = h@W_e1[:H]+b_e1 (b_e1 folded); zj = h@W_e1[H:]
// grid 1024 x 256: block = 4 rows, wave qu owns row, lane hh owns column.
// x row via wave-uniform s_load; weights streamed (L1-shared across waves).
// ---------------------------------------------------------------------------
__global__ __launch_bounds__(256) void encode_kernel(
    const float* __restrict__ x, const float* __restrict__ W_enc,
    const float* __restrict__ b_enc, const float* __restrict__ W_e1,
    const float* __restrict__ b_e1,
    float* __restrict__ h, float* __restrict__ zi, float* __restrict__ zj)
{
    const int t = threadIdx.x;
    const int hh = t & 63;
    const int qu = __builtin_amdgcn_readfirstlane(t >> 6);
    const int gR = blockIdx.x * 4 + qu;           // 0..B*N-1

    const float* xrow = x + gR * FF;              // wave-uniform -> s_load
    float acc = b_enc[hh];
#pragma unroll
    for (int k = 0; k < FF; ++k)
        acc = fmaf(xrow[k], W_enc[k * HH + hh], acc);
    const float hval = fmaxf(acc, 0.f);
    h[gR * HH + hh] = hval;

    float z1 = b_e1[hh], z2 = 0.f;
#pragma unroll 8
    for (int k = 0; k < HH; ++k) {
        const float hk = lane_bcast(hval, k);
        z1 = fmaf(hk, W_e1[k * HH + hh], z1);
        z2 = fmaf(hk, W_e1[(HH + k) * HH + hh], z2);
    }
    zi[gR * HH + hh] = z1;
    zj[gR * HH + hh] = z2;
}

// ---------------------------------------------------------------------------
// adj: logits[i,j] = sum_k relu(zi[i,k]+zj[j,k])*W_e2[k]+b_e2, diag -inf,
// softmax over j.  grid 1024 x 256: block = (b, 4 rows).  Wave qu owns
// j-quarter [128qu,128qu+128): lane tj handles j0=128qu+tj, j1=j0+64, for
// all 4 rows.  zi via wave-uniform s_loads; zj staged in k-slices
// zjs[512][17] (lane stride 17, coprime 32 -> conflict-free).
// ---------------------------------------------------------------------------
__global__ __launch_bounds__(256) void adj_kernel(
    const float* __restrict__ zi, const float* __restrict__ zj,
    const float* __restrict__ W_e2, const float* __restrict__ b_e2,
    float* __restrict__ adj)
{
    const int b = blockIdx.x >> 7;
    const int i0 = (blockIdx.x & 127) << 2;
    const int t = threadIdx.x;
    const int qu = __builtin_amdgcn_readfirstlane(t >> 6);
    const int tj = t & 63;
    const int j0 = (qu << 7) + tj;
    const int j1 = j0 + 64;

    __shared__ float zjs[NN][17];
    __shared__ float red[4][8];

    const float be2 = b_e2[0];
    float acc0[4], acc1[4];
#pragma unroll
    for (int r = 0; r < 4; ++r) { acc0[r] = be2; acc1[r] = be2; }

    const float* zib = zi + (b * NN + i0) * HH;   // wave-uniform -> s_load

    for (int kp = 0; kp < 4; ++kp) {
        __syncthreads();
        for (int idx = t; idx < NN * 16; idx += 256) {
            const int row = idx >> 4, c = idx & 15;
            zjs[row][c] = zj[(b * NN + row) * HH + (kp << 4) + c];
        }
        __syncthreads();
#pragma unroll
        for (int c = 0; c < 16; ++c) {
            const int k = (kp << 4) + c;
            const float w = W_e2[k];
            const float zj0 = zjs[j0][c];
            const float zj1 = zjs[j1][c];
#pragma unroll
            for (int r = 0; r < 4; ++r) {
                const float zv = zib[r * HH + k];
                acc0[r] = fmaf(fmaxf(zv + zj0, 0.f), w, acc0[r]);
                acc1[r] = fmaf(fmaxf(zv + zj1, 0.f), w, acc1[r]);
            }
        }
    }

#pragma unroll
    for (int r = 0; r < 4; ++r) {
        const int irow = i0 + r;
        if (j0 == irow) acc0[r] = NEG_BIG;
        if (j1 == irow) acc1[r] = NEG_BIG;
    }

    float wmax[4];
#pragma unroll
    for (int r = 0; r < 4; ++r) {
        float m = fmaxf(acc0[r], acc1[r]);
#pragma unroll
        for (int off = 32; off >= 1; off >>= 1) m = fmaxf(m, __shfl_xor(m, off));
        wmax[r] = m;
    }
    if (tj == 0) {
#pragma unroll
        for (int r = 0; r < 4; ++r) red[qu][r] = wmax[r];
    }
    __syncthreads();
    float M[4];
#pragma unroll
    for (int r = 0; r < 4; ++r)
        M[r] = fmaxf(fmaxf(red[0][r], red[1][r]), fmaxf(red[2][r], red[3][r]));
    __syncthreads();   // WAR on red

    float e0[4], e1[4];
#pragma unroll
    for (int r = 0; r < 4; ++r) {
        e0[r] = __expf(acc0[r] - M[r]);
        e1[r] = __expf(acc1[r] - M[r]);
        float s = e0[r] + e1[r];
#pragma unroll
        for (int off = 32; off >= 1; off >>= 1) s += __shfl_xor(s, off);
        if (tj == 0) red[qu][r] = s;
    }
    __syncthreads();
#pragma unroll
    for (int r = 0; r < 4; ++r) {
        const float inv = 1.0f / (red[0][r] + red[1][r] + red[2][r] + red[3][r]);
        float* arow = adj + ((size_t)(b * NN + i0 + r)) * NN;
        arow[j0] = e0[r] * inv;
        arow[j1] = e1[r] * inv;
    }
}

// ---------------------------------------------------------------------------
// layer (msg + GRU fused): m = adj@h; mm = relu(m@Wmsg+b); gates; GRU.
// grid 1024 x 256: block = (b, 4 rows); wave qu owns row, lane hh owns col.
// adj row via wave-uniform s_loads; h / weights streamed coalesced (L1
// shared across the block's 4 waves); broadcasts via v_readlane.  No LDS.
// ---------------------------------------------------------------------------
__global__ __launch_bounds__(256) void layer_kernel(
    const float* __restrict__ adjw, const float* __restrict__ h_in,
    const float* __restrict__ Wmsg, const float* __restrict__ bmsg,
    const float* __restrict__ Wih, const float* __restrict__ bih,
    const float* __restrict__ Whh, const float* __restrict__ bhh,
    float* __restrict__ h_out)
{
    const int b = blockIdx.x >> 7;
    const int i0 = (blockIdx.x & 127) << 2;
    const int t = threadIdx.x;
    const int hh = t & 63;
    const int qu = __builtin_amdgcn_readfirstlane(t >> 6);
    const int gR = b * NN + i0 + qu;

    const float hv = h_in[gR * HH + hh];
    const float* arow = adjw + (size_t)gR * NN;   // wave-uniform -> s_load
    const float* hb = h_in + (size_t)b * NN * HH;

    // m = adj @ h : 4 split chains, 8 loads in flight after unroll
    float macc[4] = {0.f, 0.f, 0.f, 0.f};
#pragma unroll 2
    for (int j = 0; j < NN; j += 4) {
        macc[0] = fmaf(arow[j],     hb[(j)     * HH + hh], macc[0]);
        macc[1] = fmaf(arow[j + 1], hb[(j + 1) * HH + hh], macc[1]);
        macc[2] = fmaf(arow[j + 2], hb[(j + 2) * HH + hh], macc[2]);
        macc[3] = fmaf(arow[j + 3], hb[(j + 3) * HH + hh], macc[3]);
    }
    const float m = (macc[0] + macc[1]) + (macc[2] + macc[3]);

    // mm = relu(m @ Wmsg + bmsg)
    float mm0 = bmsg[hh], mm1 = 0.f;
#pragma unroll 4
    for (int k = 0; k < HH; k += 2) {
        mm0 = fmaf(lane_bcast(m, k),     Wmsg[k * HH + hh],       mm0);
        mm1 = fmaf(lane_bcast(m, k + 1), Wmsg[(k + 1) * HH + hh], mm1);
    }
    const float mmv = fmaxf(mm0 + mm1, 0.f);

    // GRU gates
    float g0 = bih[hh], g1 = bih[64 + hh], g2 = bih[128 + hh];
    float g3 = bhh[hh], g4 = bhh[64 + hh], g5 = bhh[128 + hh];
#pragma unroll 4
    for (int k = 0; k < HH; ++k) {
        const float mv = lane_bcast(mmv, k);
        const float hk = lane_bcast(hv, k);
        const float* wi = Wih + k * 192;
        const float* wh = Whh + k * 192;
        g0 = fmaf(mv, wi[hh], g0);
        g1 = fmaf(mv, wi[64 + hh], g1);
        g2 = fmaf(mv, wi[128 + hh], g2);
        g3 = fmaf(hk, wh[hh], g3);
        g4 = fmaf(hk, wh[64 + hh], g4);
        g5 = fmaf(hk, wh[128 + hh], g5);
    }
    const float rr = 1.f / (1.f + __expf(-(g0 + g3)));
    const float zz = 1.f / (1.f + __expf(-(g1 + g4)));
    const float nnv = tanhf(g2 + rr * g5);
    h_out[gR * HH + hh] = (1.f - zz) * nnv + zz * hv;
}

// ---------------------------------------------------------------------------
// readout: out[b] = mean_i(h[b,i,:]) @ W_out + b_out.  8 blocks x 1024 thr,
// wave w sums rows w, w+16, ... (32 rows each, loads pipelined).
// ---------------------------------------------------------------------------
__global__ __launch_bounds__(1024) void readout_kernel(
    const float* __restrict__ h, const float* __restrict__ W_out,
    const float* __restrict__ b_out, float* __restrict__ out)
{
    const int b = blockIdx.x;
    const int t = threadIdx.x;
    const int hh = t & 63;
    const int w = t >> 6;                 // 0..15
    __shared__ float red[16][65];

    float s = 0.f;
#pragma unroll 4
    for (int i = w; i < NN; i += 16) s += h[((size_t)(b * NN + i)) * HH + hh];
    red[w][hh] = s;
    __syncthreads();
    if (w == 0) {
        float tot = 0.f;
#pragma unroll
        for (int r = 0; r < 16; ++r) tot += red[r][hh];
        float v = tot * (1.0f / NN) * W_out[hh];
#pragma unroll
        for (int off = 32; off >= 1; off >>= 1) v += __shfl_xor(v, off);
        if (hh == 0) out[b] = v + b_out[0];
    }
}

extern "C" void kernel_launch(void* const* d_in, const int* in_sizes, int n_in,
                              void* d_out, int out_size, void* d_ws, size_t ws_size,
                              hipStream_t stream)
{
    const float* x     = (const float*)d_in[0];
    const float* W_enc = (const float*)d_in[1];
    const float* b_enc = (const float*)d_in[2];
    const float* W_e1  = (const float*)d_in[3];
    const float* b_e1  = (const float*)d_in[4];
    const float* W_e2  = (const float*)d_in[5];
    const float* b_e2  = (const float*)d_in[6];
    const float* W_msg = (const float*)d_in[7];
    const float* b_msg = (const float*)d_in[8];
    const float* W_ih  = (const float*)d_in[9];
    const float* b_ih  = (const float*)d_in[10];
    const float* W_hh  = (const float*)d_in[11];
    const float* b_hh  = (const float*)d_in[12];
    const float* W_out = (const float*)d_in[13];
    const float* b_out = (const float*)d_in[14];
    float* out = (float*)d_out;

    float* ws  = (float*)d_ws;
    float* h0  = ws;
    float* h1  = h0 + BB * NN * HH;
    float* zi  = h1 + BB * NN * HH;
    float* zj  = zi + BB * NN * HH;
    float* adjw = zj + BB * NN * HH;

    encode_kernel<<<BB * NN / 4, 256, 0, stream>>>(x, W_enc, b_enc, W_e1, b_e1, h0, zi, zj);
    adj_kernel<<<BB * (NN / 4), 256, 0, stream>>>(zi, zj, W_e2, b_e2, adjw);

    layer_kernel<<<BB * (NN / 4), 256, 0, stream>>>(
        adjw, h0, W_msg, b_msg, W_ih, b_ih, W_hh, b_hh, h1);
    layer_kernel<<<BB * (NN / 4), 256, 0, stream>>>(
        adjw, h1, W_msg + HH * HH, b_msg + HH,
        W_ih + HH * 3 * HH, b_ih + 3 * HH, W_hh + HH * 3 * HH, b_hh + 3 * HH, h0);

    readout_kernel<<<BB, 1024, 0, stream>>>(h0, W_out, b_out, out);
}